// Round 10
// baseline (5636.683 us; speedup 1.0000x reference)
//
#include <hip/hip_runtime.h>
#include <hip/hip_bf16.h>

namespace {

constexpr int B = 1024, T = 512, H = 60, G = 180, NTHR = 192;
constexpr int GR = 64;  // rows per gi-gemm block

__device__ __forceinline__ float sigm(float x) { return 1.f / (1.f + __expf(-x)); }
__device__ __forceinline__ float tanh_fast(float x) {
  x = fminf(fmaxf(x, -15.f), 15.f);
  const float e = __expf(-2.f * x);
  return (1.f - e) / (1.f + e);
}

// PINNED loads: volatile loads cannot be sunk/duplicated/rematerialized by
// the compiler, so the loaded values MUST stay live in registers across the
// t-loop. This is the structural fix for the r1-r9 coin-flip where the
// backend kept sinking weight loads into the recurrence (418us scalar @
// VGPR=48 when sunk vs 62us @ 88 when resident).
__device__ __forceinline__ float4 vload4(const float* p) {
  const volatile float* q = p;
  float4 r; r.x = q[0]; r.y = q[1]; r.z = q[2]; r.w = q[3];
  return r;
}
__device__ __forceinline__ float vload1(const float* p) {
  return *(const volatile float*)p;
}

#define ACCH(i, dst)                                                  \
  {                                                                   \
    const float4 hv = *(const float4*)&h_sh[(i) * 4];                 \
    dst = fmaf(Wh##i.x, hv.x, dst);                                   \
    dst = fmaf(Wh##i.y, hv.y, dst);                                   \
    dst = fmaf(Wh##i.z, hv.z, dst);                                   \
    dst = fmaf(Wh##i.w, hv.w, dst);                                   \
  }
#define ACCH_ALL                                                      \
  ACCH(0, c0) ACCH(1, c1) ACCH(2, c2) ACCH(3, c3)                     \
  ACCH(4, c0) ACCH(5, c1) ACCH(6, c2) ACCH(7, c3)                     \
  ACCH(8, c0) ACCH(9, c1) ACCH(10, c2) ACCH(11, c3)                   \
  ACCH(12, c0) ACCH(13, c1) ACCH(14, c2)

// ---------------------------------------------------------------------------
// Scalar-input GRU layer (F=1), weights pinned in registers via vload4.
// ---------------------------------------------------------------------------
template <bool WRITE_YS, bool WRITE_ENC>
__global__ __launch_bounds__(NTHR, 1) void gru_scalar_kernel(
    const float* __restrict__ xscalar,  // [B][T]
    const float* __restrict__ Wih,      // [180][1]
    const float* __restrict__ Whh,      // [180][60]
    const float* __restrict__ bih, const float* __restrict__ bhh,
    const float* __restrict__ h_init,   // nullptr => zeros; [b*180 + j]
    float* __restrict__ ys_out,         // [T][B][60]
    float* __restrict__ enc_out)        // pre-offset by slot; [b*180 + j]
{
  const int tid = threadIdx.x;
  const int b = blockIdx.x;

  __shared__ __align__(16) float h_sh[64];
  __shared__ float Ar[60], Az[60], Nn[60], Hn[60];
  __shared__ float xs_seq[T];

  const int rr = (tid < G) ? tid : 0;

  float4 Wh0, Wh1, Wh2, Wh3, Wh4, Wh5, Wh6, Wh7, Wh8, Wh9, Wh10, Wh11, Wh12, Wh13, Wh14;
#define LWH(i) Wh##i = vload4(&Whh[(size_t)rr * H + (i) * 4]);
  LWH(0) LWH(1) LWH(2) LWH(3) LWH(4) LWH(5) LWH(6) LWH(7)
  LWH(8) LWH(9) LWH(10) LWH(11) LWH(12) LWH(13) LWH(14)
#undef LWH
  const float wih0 = vload1(&Wih[rr]);
  const float bi = vload1(&bih[rr]);
  const float bh = vload1(&bhh[rr]);

  if (tid < H) h_sh[tid] = h_init ? h_init[(size_t)b * G + tid] : 0.f;
  if (tid >= H && tid < 64) h_sh[tid] = 0.f;
  for (int i = tid; i < T; i += NTHR) xs_seq[i] = xscalar[(size_t)b * T + i];
  __syncthreads();

  const int g = tid / H;
  const int j = tid - g * H;

  for (int t = 0; t < T; ++t) {
    if (tid < G) {
      float c0 = bh, c1 = 0.f, c2 = 0.f, c3 = 0.f;
      ACCH_ALL
      const float c = (c0 + c1) + (c2 + c3);
      const float a = fmaf(wih0, xs_seq[t], bi);
      if (g == 0)       Ar[j] = a + c;
      else if (g == 1)  Az[j] = a + c;
      else            { Nn[j] = a; Hn[j] = c; }
    }
    __syncthreads();

    if (tid < H) {
      const float rg = sigm(Ar[tid]);
      const float zg = sigm(Az[tid]);
      const float nv = tanh_fast(fmaf(rg, Hn[tid], Nn[tid]));
      const float hnew = fmaf(zg, h_sh[tid] - nv, nv);
      h_sh[tid] = hnew;
      if constexpr (WRITE_YS)
        ys_out[(size_t)t * B * H + (size_t)b * H + tid] = hnew;
    }
    __syncthreads();
  }

  if constexpr (WRITE_ENC) {
    if (tid < H) enc_out[(size_t)b * G + tid] = h_sh[tid];
  }
}

// ---------------------------------------------------------------------------
// gi GEMM: gi[row][r] = bih[r] + Wih[r].x[row], 64 rows/block (8 passes x 8
// accumulators), Wih row pinned in registers. Fully parallel.
// ---------------------------------------------------------------------------
__global__ __launch_bounds__(NTHR, 1) void gi_gemm_kernel(
    const float* __restrict__ x,      // chunk base: [row][60] contiguous
    const float* __restrict__ Wih,    // [180][60]
    const float* __restrict__ bih,
    float* __restrict__ gi)           // chunk base: [row][180]
{
  __shared__ __align__(16) float xs[GR * H];   // 15.36 KB
  const int tid = threadIdx.x;
  const size_t row0 = (size_t)blockIdx.x * GR;
  const int rr = (tid < G) ? tid : 0;

  float4 W0, W1, W2, W3, W4, W5, W6, W7, W8, W9, W10, W11, W12, W13, W14;
#define LW(i) W##i = vload4(&Wih[(size_t)rr * H + (i) * 4]);
  LW(0) LW(1) LW(2) LW(3) LW(4) LW(5) LW(6) LW(7)
  LW(8) LW(9) LW(10) LW(11) LW(12) LW(13) LW(14)
#undef LW
  const float bi = vload1(&bih[rr]);

  {
    const float4* s4 = (const float4*)(x + row0 * H);
    float4* d4 = (float4*)xs;
#pragma unroll
    for (int q = 0; q < 5; ++q) d4[q * NTHR + tid] = s4[q * NTHR + tid];  // 960
  }
  __syncthreads();

#define GX(s, a)                                                      \
  {                                                                   \
    const float4 xv = *(const float4*)&xb[(s) * H + 4 * kk];          \
    a = fmaf(w.x, xv.x, a); a = fmaf(w.y, xv.y, a);                   \
    a = fmaf(w.z, xv.z, a); a = fmaf(w.w, xv.w, a);                   \
  }
#define PASS(p)                                                       \
  {                                                                   \
    const float* xb = xs + (p) * 8 * H;                               \
    float a0 = bi, a1 = bi, a2 = bi, a3 = bi;                         \
    float a4 = bi, a5 = bi, a6 = bi, a7 = bi;                         \
    _Pragma("unroll")                                                 \
    for (int kk = 0; kk < 15; ++kk) {                                 \
      float4 w;                                                       \
      switch (kk) {                                                   \
        case 0: w = W0; break;   case 1: w = W1; break;               \
        case 2: w = W2; break;   case 3: w = W3; break;               \
        case 4: w = W4; break;   case 5: w = W5; break;               \
        case 6: w = W6; break;   case 7: w = W7; break;               \
        case 8: w = W8; break;   case 9: w = W9; break;               \
        case 10: w = W10; break; case 11: w = W11; break;             \
        case 12: w = W12; break; case 13: w = W13; break;             \
        default: w = W14; break;                                      \
      }                                                               \
      GX(0, a0) GX(1, a1) GX(2, a2) GX(3, a3)                         \
      GX(4, a4) GX(5, a5) GX(6, a6) GX(7, a7)                         \
    }                                                                 \
    if (tid < G) {                                                    \
      float* o = gi + (row0 + (p) * 8) * G + rr;                      \
      o[0 * G] = a0; o[1 * G] = a1; o[2 * G] = a2; o[3 * G] = a3;     \
      o[4 * G] = a4; o[5 * G] = a5; o[6 * G] = a6; o[7 * G] = a7;     \
    }                                                                 \
  }
  PASS(0) PASS(1) PASS(2) PASS(3) PASS(4) PASS(5) PASS(6) PASS(7)
#undef PASS
#undef GX
}

// ---------------------------------------------------------------------------
// Recurrent layer consuming precomputed gi; Whh row pinned in registers;
// gi streamed with 4-deep register prefetch.
// ---------------------------------------------------------------------------
template <bool WRITE_YS, bool WRITE_PRED>
__global__ __launch_bounds__(NTHR, 1) void gru_rec_kernel(
    const float* __restrict__ gi,      // [nsteps][B][180] chunk-local
    const float* __restrict__ Whh, const float* __restrict__ bhh,
    const float* __restrict__ h_in, int h_in_stride,  // null => zeros
    float* __restrict__ ys_out,        // chunk base [nsteps][B][60]
    float* __restrict__ h_out,         // [B][60] carry
    float* __restrict__ enc_out,       // [b*180+j] or null
    float* __restrict__ pred_out,      // [B][T] (if WRITE_PRED)
    const float* __restrict__ linW, const float* __restrict__ linb,
    int t0, int nsteps)
{
  const int tid = threadIdx.x;
  const int b = blockIdx.x;

  __shared__ __align__(16) float h_sh[64];
  __shared__ float Ar[60], Az[60], Nn[60], Hn[60];
  __shared__ float pv[64];

  const int rr = (tid < G) ? tid : 0;

  float4 Wh0, Wh1, Wh2, Wh3, Wh4, Wh5, Wh6, Wh7, Wh8, Wh9, Wh10, Wh11, Wh12, Wh13, Wh14;
#define LWH(i) Wh##i = vload4(&Whh[(size_t)rr * H + (i) * 4]);
  LWH(0) LWH(1) LWH(2) LWH(3) LWH(4) LWH(5) LWH(6) LWH(7)
  LWH(8) LWH(9) LWH(10) LWH(11) LWH(12) LWH(13) LWH(14)
#undef LWH
  const float bh = vload1(&bhh[rr]);

  float linw = 0.f, lb = 0.f;
  if constexpr (WRITE_PRED) {
    linw = vload1(&linW[tid < H ? tid : 0]);
    lb = vload1(&linb[0]);
  }

  if (tid < H) h_sh[tid] = h_in ? h_in[(size_t)b * h_in_stride + tid] : 0.f;
  if (tid >= H && tid < 64) h_sh[tid] = 0.f;
  __syncthreads();

  const int g = rr / H;
  const int j = rr - g * H;
  const bool rowact = tid < G;

  float g0 = 0.f, g1 = 0.f, g2 = 0.f, g3 = 0.f;
  if (rowact) {
    g0 = gi[((size_t)0 * B + b) * G + rr];
    g1 = gi[((size_t)1 * B + b) * G + rr];
    g2 = gi[((size_t)2 * B + b) * G + rr];
    g3 = gi[((size_t)3 * B + b) * G + rr];
  }

  for (int s = 0; s < nsteps; ++s) {
    float gn = 0.f;
    if (rowact && s + 4 < nsteps) gn = gi[((size_t)(s + 4) * B + b) * G + rr];

    if (rowact) {
      float c0 = bh, c1 = 0.f, c2 = 0.f, c3 = 0.f;
      ACCH_ALL
      const float c = (c0 + c1) + (c2 + c3);
      const float a = g0;
      if (g == 0)       Ar[j] = a + c;
      else if (g == 1)  Az[j] = a + c;
      else            { Nn[j] = a; Hn[j] = c; }
    }
    g0 = g1; g1 = g2; g2 = g3; g3 = gn;
    __syncthreads();

    if (tid < H) {
      const float rg = sigm(Ar[tid]);
      const float zg = sigm(Az[tid]);
      const float nv = tanh_fast(fmaf(rg, Hn[tid], Nn[tid]));
      const float hnew = fmaf(zg, h_sh[tid] - nv, nv);
      h_sh[tid] = hnew;
      if constexpr (WRITE_YS)
        ys_out[(size_t)s * B * H + (size_t)b * H + tid] = hnew;
      if constexpr (WRITE_PRED) pv[tid] = hnew * linw;
    }
    __syncthreads();

    if constexpr (WRITE_PRED) {
      if (tid < 64) {
        float v = (tid < H) ? pv[tid] : 0.f;
#pragma unroll
        for (int o = 32; o; o >>= 1) v += __shfl_xor(v, o);
        if (tid == 0) pred_out[(size_t)b * T + t0 + s] = v + lb;
      }
    }
  }

  if (tid < H) {
    h_out[(size_t)b * H + tid] = h_sh[tid];
    if (enc_out) enc_out[(size_t)b * G + tid] = h_sh[tid];
  }
}

template <bool WRITE_YS, bool WRITE_PRED>
void run_vec_layer(const float* Wih, const float* bih,
                   const float* Whh, const float* bhh,
                   const float* h_init_slot,          // stride 180, may be null
                   float* enc_slot_out,               // may be null
                   float* ysA, float* gic, float* hio,
                   float* pred, const float* linW, const float* linb,
                   int nch, hipStream_t stream) {
  const int tn = T / nch;
  for (int c = 0; c < nch; ++c) {
    const int t0 = c * tn;
    gi_gemm_kernel<<<dim3((tn * B) / GR), dim3(NTHR), 0, stream>>>(
        ysA + (size_t)t0 * B * H, Wih, bih, gic);
    gru_rec_kernel<WRITE_YS, WRITE_PRED><<<dim3(B), dim3(NTHR), 0, stream>>>(
        gic, Whh, bhh,
        c ? hio : h_init_slot, c ? H : G,
        ysA + (size_t)t0 * B * H, hio,
        (c == nch - 1) ? enc_slot_out : nullptr,
        pred, linW, linb, t0, tn);
  }
}

}  // namespace

extern "C" void kernel_launch(void* const* d_in, const int* in_sizes, int n_in,
                              void* d_out, int out_size, void* d_ws, size_t ws_size,
                              hipStream_t stream) {
  const float* inputs  = (const float*)d_in[0];
  const float* outputs = (const float*)d_in[1];
  const float* eW_ih0 = (const float*)d_in[2];  const float* eW_hh0 = (const float*)d_in[3];
  const float* eb_ih0 = (const float*)d_in[4];  const float* eb_hh0 = (const float*)d_in[5];
  const float* eW_ih1 = (const float*)d_in[6];  const float* eW_hh1 = (const float*)d_in[7];
  const float* eb_ih1 = (const float*)d_in[8];  const float* eb_hh1 = (const float*)d_in[9];
  const float* eW_ih2 = (const float*)d_in[10]; const float* eW_hh2 = (const float*)d_in[11];
  const float* eb_ih2 = (const float*)d_in[12]; const float* eb_hh2 = (const float*)d_in[13];
  const float* c1_Wih = (const float*)d_in[14]; const float* c1_Whh = (const float*)d_in[15];
  const float* c1_bih = (const float*)d_in[16]; const float* c1_bhh = (const float*)d_in[17];
  const float* c2_Wih = (const float*)d_in[18]; const float* c2_Whh = (const float*)d_in[19];
  const float* c2_bih = (const float*)d_in[20]; const float* c2_bhh = (const float*)d_in[21];
  const float* c3_Wih = (const float*)d_in[22]; const float* c3_Whh = (const float*)d_in[23];
  const float* c3_bih = (const float*)d_in[24]; const float* c3_bhh = (const float*)d_in[25];
  const float* lin_W  = (const float*)d_in[26]; const float* lin_b  = (const float*)d_in[27];

  float* pred = (float*)d_out;                 // [B][T]
  float* enc  = pred + (size_t)B * T;          // [B][3][60]

  const size_t seq = (size_t)T * B * H;        // ys elements

  int nch = 64;
  for (int c : {1, 2, 4, 8, 16, 32}) {
    const size_t need = seq * 4 + (size_t)(T / c) * B * G * 4 + (size_t)B * H * 4;
    if (ws_size >= need) { nch = c; break; }
  }

  float* ysA = (float*)d_ws;                        // [T][B][60] fp32
  float* gic = ysA + seq;                           // [(T/nch)][B][180] fp32
  float* hio = gic + (size_t)(T / nch) * B * G;     // [B][60] fp32

  // ---- encoder ----
  gru_scalar_kernel<true, true><<<dim3(B), dim3(NTHR), 0, stream>>>(
      inputs, eW_ih0, eW_hh0, eb_ih0, eb_hh0, nullptr, ysA, enc + 0);
  run_vec_layer<true, false>(eW_ih1, eb_ih1, eW_hh1, eb_hh1, nullptr, enc + 60,
                             ysA, gic, hio, pred, lin_W, lin_b, nch, stream);
  run_vec_layer<false, false>(eW_ih2, eb_ih2, eW_hh2, eb_hh2, nullptr, enc + 120,
                              ysA, gic, hio, pred, lin_W, lin_b, nch, stream);

  // ---- decoder: h1<-enc[2], h2<-enc[1], h3<-enc[0] ----
  gru_scalar_kernel<true, false><<<dim3(B), dim3(NTHR), 0, stream>>>(
      outputs, c1_Wih, c1_Whh, c1_bih, c1_bhh, enc + 120, ysA, nullptr);
  run_vec_layer<true, false>(c2_Wih, c2_bih, c2_Whh, c2_bhh, enc + 60, nullptr,
                             ysA, gic, hio, pred, lin_W, lin_b, nch, stream);
  run_vec_layer<false, true>(c3_Wih, c3_bih, c3_Whh, c3_bhh, enc + 0, nullptr,
                             ysA, gic, hio, pred, lin_W, lin_b, nch, stream);
}

// Round 11
// 5203.952 us; speedup vs baseline: 1.0832x; 1.0832x over previous
//
#include <hip/hip_runtime.h>
#include <hip/hip_bf16.h>

namespace {

constexpr int B = 1024, T = 512, H = 60, G = 180, NTHR = 192;
constexpr int GR = 64;  // rows per gi-gemm block

__device__ __forceinline__ float sigm(float x) { return 1.f / (1.f + __expf(-x)); }
__device__ __forceinline__ float tanh_fast(float x) {
  x = fminf(fmaxf(x, -15.f), 15.f);
  const float e = __expf(-2.f * x);
  return (1.f - e) / (1.f + e);
}

#define ACCH(i, dst)                                                  \
  {                                                                   \
    const float4 hv = *(const float4*)&h_sh[(i) * 4];                 \
    dst = fmaf(Wh##i.x, hv.x, dst);                                   \
    dst = fmaf(Wh##i.y, hv.y, dst);                                   \
    dst = fmaf(Wh##i.z, hv.z, dst);                                   \
    dst = fmaf(Wh##i.w, hv.w, dst);                                   \
  }
#define ACCH_ALL                                                      \
  ACCH(0, c0) ACCH(1, c1) ACCH(2, c2) ACCH(3, c3)                     \
  ACCH(4, c0) ACCH(5, c1) ACCH(6, c2) ACCH(7, c3)                     \
  ACCH(8, c0) ACCH(9, c1) ACCH(10, c2) ACCH(11, c3)                   \
  ACCH(12, c0) ACCH(13, c1) ACCH(14, c2)

// ---------------------------------------------------------------------------
// gi GEMM: gi[row][r] = bih[r] + Wih[r].x[row], 64 rows/block. Fully
// parallel. amdgpu_waves_per_eu(1,3): the scheduler's occupancy TARGET is
// <=3 waves/EU -> VGPR budget ~170, so the 60-float Wih row stays resident
// (r9/r10: default target squeezed to 48 VGPR and spilled/sank the weights).
// ---------------------------------------------------------------------------
__global__ __launch_bounds__(NTHR) __attribute__((amdgpu_waves_per_eu(1, 3)))
void gi_gemm_kernel(
    const float* __restrict__ x,      // chunk base: [row][60] contiguous
    const float* __restrict__ Wih,    // [180][60]
    const float* __restrict__ bih,
    float* __restrict__ gi)           // chunk base: [row][180]
{
  __shared__ __align__(16) float xs[GR * H];   // 15.36 KB
  const int tid = threadIdx.x;
  const size_t row0 = (size_t)blockIdx.x * GR;
  const int rr = (tid < G) ? tid : 0;

  float4 W0, W1, W2, W3, W4, W5, W6, W7, W8, W9, W10, W11, W12, W13, W14;
#define LW(i) W##i = *(const float4*)&Wih[(size_t)rr * H + (i) * 4];
  LW(0) LW(1) LW(2) LW(3) LW(4) LW(5) LW(6) LW(7)
  LW(8) LW(9) LW(10) LW(11) LW(12) LW(13) LW(14)
#undef LW
  const float bi = bih[rr];

  {
    const float4* s4 = (const float4*)(x + row0 * H);
    float4* d4 = (float4*)xs;
#pragma unroll
    for (int q = 0; q < 5; ++q) d4[q * NTHR + tid] = s4[q * NTHR + tid];  // 960
  }
  __syncthreads();

#define GX(s, a)                                                      \
  {                                                                   \
    const float4 xv = *(const float4*)&xb[(s) * H + 4 * kk];          \
    a = fmaf(w.x, xv.x, a); a = fmaf(w.y, xv.y, a);                   \
    a = fmaf(w.z, xv.z, a); a = fmaf(w.w, xv.w, a);                   \
  }
#define PASS(p)                                                       \
  {                                                                   \
    const float* xb = xs + (p) * 8 * H;                               \
    float a0 = bi, a1 = bi, a2 = bi, a3 = bi;                         \
    float a4 = bi, a5 = bi, a6 = bi, a7 = bi;                         \
    _Pragma("unroll")                                                 \
    for (int kk = 0; kk < 15; ++kk) {                                 \
      float4 w;                                                       \
      switch (kk) {                                                   \
        case 0: w = W0; break;   case 1: w = W1; break;               \
        case 2: w = W2; break;   case 3: w = W3; break;               \
        case 4: w = W4; break;   case 5: w = W5; break;               \
        case 6: w = W6; break;   case 7: w = W7; break;               \
        case 8: w = W8; break;   case 9: w = W9; break;               \
        case 10: w = W10; break; case 11: w = W11; break;             \
        case 12: w = W12; break; case 13: w = W13; break;             \
        default: w = W14; break;                                      \
      }                                                               \
      GX(0, a0) GX(1, a1) GX(2, a2) GX(3, a3)                         \
      GX(4, a4) GX(5, a5) GX(6, a6) GX(7, a7)                         \
    }                                                                 \
    if (tid < G) {                                                    \
      float* o = gi + (row0 + (p) * 8) * G + rr;                      \
      o[0 * G] = a0; o[1 * G] = a1; o[2 * G] = a2; o[3 * G] = a3;     \
      o[4 * G] = a4; o[5 * G] = a5; o[6 * G] = a6; o[7 * G] = a7;     \
    }                                                                 \
  }
  PASS(0) PASS(1) PASS(2) PASS(3) PASS(4) PASS(5) PASS(6) PASS(7)
#undef PASS
#undef GX
}

// ---------------------------------------------------------------------------
// Recurrent GRU chunk. SCALAR_X: input term computed in-kernel from the F=1
// stream (the proven r5 fused form, no gi producer needed). Otherwise `a`
// streams from precomputed gi with a 4-deep register prefetch. Whh row in
// registers; waves_per_eu(1,3) keeps the allocator's budget at ~170 VGPR.
// ---------------------------------------------------------------------------
template <bool SCALAR_X, bool WRITE_YS, bool WRITE_PRED>
__global__ __launch_bounds__(NTHR) __attribute__((amdgpu_waves_per_eu(1, 3)))
void gru_rec_kernel(
    const float* __restrict__ gi,      // [nsteps][B][180] chunk-local (!SCALAR_X)
    const float* __restrict__ xsc,     // [B][T] (SCALAR_X)
    const float* __restrict__ Wih1,    // [180] (SCALAR_X)
    const float* __restrict__ bih1,    // [180] (SCALAR_X)
    const float* __restrict__ Whh, const float* __restrict__ bhh,
    const float* __restrict__ h_in, int h_in_stride,  // null => zeros
    float* __restrict__ ys_out,        // chunk base [nsteps][B][60]
    float* __restrict__ h_out,         // [B][60] carry
    float* __restrict__ enc_out,       // [b*180+j] or null
    float* __restrict__ pred_out,      // [B][T] (WRITE_PRED)
    const float* __restrict__ linW, const float* __restrict__ linb,
    int t0, int nsteps)
{
  const int tid = threadIdx.x;
  const int b = blockIdx.x;

  __shared__ __align__(16) float h_sh[64];
  __shared__ float Ar[60], Az[60], Nn[60], Hn[60];
  __shared__ float xs_seq[T];
  __shared__ float pv[64];

  const int rr = (tid < G) ? tid : 0;

  float4 Wh0, Wh1, Wh2, Wh3, Wh4, Wh5, Wh6, Wh7, Wh8, Wh9, Wh10, Wh11, Wh12, Wh13, Wh14;
#define LWH(i) Wh##i = *(const float4*)&Whh[(size_t)rr * H + (i) * 4];
  LWH(0) LWH(1) LWH(2) LWH(3) LWH(4) LWH(5) LWH(6) LWH(7)
  LWH(8) LWH(9) LWH(10) LWH(11) LWH(12) LWH(13) LWH(14)
#undef LWH
  const float bh = bhh[rr];

  float wih0 = 0.f, bi0 = 0.f;
  if constexpr (SCALAR_X) {
    wih0 = Wih1[rr];
    bi0 = bih1[rr];
  }

  float linw = 0.f, lb = 0.f;
  if constexpr (WRITE_PRED) {
    linw = linW[tid < H ? tid : 0];
    lb = linb[0];
  }

  if (tid < H) h_sh[tid] = h_in ? h_in[(size_t)b * h_in_stride + tid] : 0.f;
  if (tid >= H && tid < 64) h_sh[tid] = 0.f;
  if constexpr (SCALAR_X) {
    for (int i = tid; i < nsteps; i += NTHR)
      xs_seq[i] = xsc[(size_t)b * T + t0 + i];
  }
  __syncthreads();

  const int g = rr / H;
  const int j = rr - g * H;
  const bool rowact = tid < G;

  float g0 = 0.f, g1 = 0.f, g2 = 0.f, g3 = 0.f;
  if constexpr (!SCALAR_X) {
    if (rowact) {
      g0 = gi[((size_t)0 * B + b) * G + rr];
      g1 = gi[((size_t)1 * B + b) * G + rr];
      g2 = gi[((size_t)2 * B + b) * G + rr];
      g3 = gi[((size_t)3 * B + b) * G + rr];
    }
  }

  for (int s = 0; s < nsteps; ++s) {
    float gn = 0.f;
    if constexpr (!SCALAR_X) {
      if (rowact && s + 4 < nsteps) gn = gi[((size_t)(s + 4) * B + b) * G + rr];
    }

    if (rowact) {
      float c0 = bh, c1 = 0.f, c2 = 0.f, c3 = 0.f;
      ACCH_ALL
      const float c = (c0 + c1) + (c2 + c3);
      float a;
      if constexpr (SCALAR_X) a = fmaf(wih0, xs_seq[s], bi0);
      else                    a = g0;
      if (g == 0)       Ar[j] = a + c;
      else if (g == 1)  Az[j] = a + c;
      else            { Nn[j] = a; Hn[j] = c; }
    }
    if constexpr (!SCALAR_X) { g0 = g1; g1 = g2; g2 = g3; g3 = gn; }
    __syncthreads();

    if (tid < H) {
      const float rg = sigm(Ar[tid]);
      const float zg = sigm(Az[tid]);
      const float nv = tanh_fast(fmaf(rg, Hn[tid], Nn[tid]));
      const float hnew = fmaf(zg, h_sh[tid] - nv, nv);
      h_sh[tid] = hnew;
      if constexpr (WRITE_YS)
        ys_out[(size_t)s * B * H + (size_t)b * H + tid] = hnew;
      if constexpr (WRITE_PRED) pv[tid] = hnew * linw;
    }
    __syncthreads();

    if constexpr (WRITE_PRED) {
      if (tid < 64) {
        float v = (tid < H) ? pv[tid] : 0.f;
#pragma unroll
        for (int o = 32; o; o >>= 1) v += __shfl_xor(v, o);
        if (tid == 0) pred_out[(size_t)b * T + t0 + s] = v + lb;
      }
    }
  }

  if (tid < H) {
    h_out[(size_t)b * H + tid] = h_sh[tid];
    if (enc_out) enc_out[(size_t)b * G + tid] = h_sh[tid];
  }
}

// ---------------------------------------------------------------------------
// One layer = nch chunks of (optional gemm -> rec). For vec layers the rec
// overwrites the ys chunk the gemm just consumed, so one ys buffer + one gi
// chunk buffer suffice.
// ---------------------------------------------------------------------------
template <bool SCALAR_X, bool WRITE_YS, bool WRITE_PRED>
void run_layer(const float* xsc,                    // [B][T] (SCALAR_X)
               const float* Wih, const float* bih,
               const float* Whh, const float* bhh,
               const float* h_init_slot,            // stride 180, may be null
               float* enc_slot_out,                 // may be null
               float* ysA, float* gic, float* hio,
               float* pred, const float* linW, const float* linb,
               int nch, hipStream_t stream) {
  const int tn = T / nch;
  for (int c = 0; c < nch; ++c) {
    const int t0 = c * tn;
    if constexpr (!SCALAR_X) {
      gi_gemm_kernel<<<dim3((tn * B) / GR), dim3(NTHR), 0, stream>>>(
          ysA + (size_t)t0 * B * H, Wih, bih, gic);
    }
    gru_rec_kernel<SCALAR_X, WRITE_YS, WRITE_PRED>
        <<<dim3(B), dim3(NTHR), 0, stream>>>(
        gic, xsc, Wih, bih, Whh, bhh,
        c ? hio : h_init_slot, c ? H : G,
        ysA + (size_t)t0 * B * H, hio,
        (c == nch - 1) ? enc_slot_out : nullptr,
        pred, linW, linb, t0, tn);
  }
}

}  // namespace

extern "C" void kernel_launch(void* const* d_in, const int* in_sizes, int n_in,
                              void* d_out, int out_size, void* d_ws, size_t ws_size,
                              hipStream_t stream) {
  const float* inputs  = (const float*)d_in[0];
  const float* outputs = (const float*)d_in[1];
  const float* eW_ih0 = (const float*)d_in[2];  const float* eW_hh0 = (const float*)d_in[3];
  const float* eb_ih0 = (const float*)d_in[4];  const float* eb_hh0 = (const float*)d_in[5];
  const float* eW_ih1 = (const float*)d_in[6];  const float* eW_hh1 = (const float*)d_in[7];
  const float* eb_ih1 = (const float*)d_in[8];  const float* eb_hh1 = (const float*)d_in[9];
  const float* eW_ih2 = (const float*)d_in[10]; const float* eW_hh2 = (const float*)d_in[11];
  const float* eb_ih2 = (const float*)d_in[12]; const float* eb_hh2 = (const float*)d_in[13];
  const float* c1_Wih = (const float*)d_in[14]; const float* c1_Whh = (const float*)d_in[15];
  const float* c1_bih = (const float*)d_in[16]; const float* c1_bhh = (const float*)d_in[17];
  const float* c2_Wih = (const float*)d_in[18]; const float* c2_Whh = (const float*)d_in[19];
  const float* c2_bih = (const float*)d_in[20]; const float* c2_bhh = (const float*)d_in[21];
  const float* c3_Wih = (const float*)d_in[22]; const float* c3_Whh = (const float*)d_in[23];
  const float* c3_bih = (const float*)d_in[24]; const float* c3_bhh = (const float*)d_in[25];
  const float* lin_W  = (const float*)d_in[26]; const float* lin_b  = (const float*)d_in[27];

  float* pred = (float*)d_out;                 // [B][T]
  float* enc  = pred + (size_t)B * T;          // [B][3][60]

  const size_t seq = (size_t)T * B * H;        // ys elements

  int nch = 64;
  for (int c : {1, 2, 4, 8, 16, 32}) {
    const size_t need = seq * 4 + (size_t)(T / c) * B * G * 4 + (size_t)B * H * 4;
    if (ws_size >= need) { nch = c; break; }
  }

  float* ysA = (float*)d_ws;                        // [T][B][60] fp32
  float* gic = ysA + seq;                           // [(T/nch)][B][180] fp32
  float* hio = gic + (size_t)(T / nch) * B * G;     // [B][60] fp32

  // ---- encoder ----
  run_layer<true, true, false>(inputs, eW_ih0, eb_ih0, eW_hh0, eb_hh0,
                               nullptr, enc + 0,
                               ysA, gic, hio, pred, lin_W, lin_b, nch, stream);
  run_layer<false, true, false>(nullptr, eW_ih1, eb_ih1, eW_hh1, eb_hh1,
                                nullptr, enc + 60,
                                ysA, gic, hio, pred, lin_W, lin_b, nch, stream);
  run_layer<false, false, false>(nullptr, eW_ih2, eb_ih2, eW_hh2, eb_hh2,
                                 nullptr, enc + 120,
                                 ysA, gic, hio, pred, lin_W, lin_b, nch, stream);

  // ---- decoder: h1<-enc[2], h2<-enc[1], h3<-enc[0] ----
  run_layer<true, true, false>(outputs, c1_Wih, c1_bih, c1_Whh, c1_bhh,
                               enc + 120, nullptr,
                               ysA, gic, hio, pred, lin_W, lin_b, nch, stream);
  run_layer<false, true, false>(nullptr, c2_Wih, c2_bih, c2_Whh, c2_bhh,
                                enc + 60, nullptr,
                                ysA, gic, hio, pred, lin_W, lin_b, nch, stream);
  run_layer<false, false, true>(nullptr, c3_Wih, c3_bih, c3_Whh, c3_bhh,
                                enc + 0, nullptr,
                                ysA, gic, hio, pred, lin_W, lin_b, nch, stream);
}

// Round 12
// 5198.287 us; speedup vs baseline: 1.0843x; 1.0011x over previous
//
#include <hip/hip_runtime.h>
#include <hip/hip_bf16.h>

namespace {

constexpr int B = 1024, T = 512, H = 60, G = 180;
constexpr int NTHR = 384;  // 6 waves; pair-split: thread = (row, half)
constexpr int GR = 64;     // rows per gi-gemm block

__device__ __forceinline__ float sigm(float x) { return 1.f / (1.f + __expf(-x)); }
__device__ __forceinline__ float tanh_fast(float x) {
  x = fminf(fmaxf(x, -15.f), 15.f);
  const float e = __expf(-2.f * x);
  return (1.f - e) / (1.f + e);
}

// Pair-split weight layout: thread (row, half) holds 8 float4s of row `row`.
//   half0: cols 0..31.  half1: loaded from col 28, first float4 zeroed ->
//   effective cols 32..59. No overlap, no out-of-bounds (28..59 < 60).
// Peak live state ~55 VGPR < the allocator's worst-case 64-grant, so weight
// residency is STRUCTURAL, not a regalloc lottery (r1-r11's failure mode:
// 60 floats/thread -> sunk/spilled loads whenever the module phase changed).

#define LOADW8(PTR)                                                   \
  W0 = *(const float4*)((PTR) + 0);  W1 = *(const float4*)((PTR) + 4);  \
  W2 = *(const float4*)((PTR) + 8);  W3 = *(const float4*)((PTR) + 12); \
  W4 = *(const float4*)((PTR) + 16); W5 = *(const float4*)((PTR) + 20); \
  W6 = *(const float4*)((PTR) + 24); W7 = *(const float4*)((PTR) + 28); \
  if (half) W0 = make_float4(0.f, 0.f, 0.f, 0.f);

// ---------------------------------------------------------------------------
// gi GEMM: gi[row][r] = bih[r] + Wih[r].x[row]; fully parallel; 64 rows/block
// in 8 passes of 8 rows; pair-split dots combined via shfl_xor(1).
// ---------------------------------------------------------------------------
__global__ __launch_bounds__(NTHR, 1) void gi_gemm_kernel(
    const float* __restrict__ x,      // chunk base: [row][60] contiguous
    const float* __restrict__ Wih,    // [180][60]
    const float* __restrict__ bih,
    float* __restrict__ gi)           // chunk base: [row][180]
{
  __shared__ __align__(16) float4 xs4[GR * 16];  // rows padded to 16 float4
  const int tid = threadIdx.x;
  const size_t row0 = (size_t)blockIdx.x * GR;
  const bool act = tid < 2 * G;
  const int row = (act ? tid : 0) >> 1;
  const int half = tid & 1;

  float4 W0, W1, W2, W3, W4, W5, W6, W7;
  LOADW8(&Wih[(size_t)row * H + half * 28]);
  const float bi = half ? 0.f : bih[row];

  {  // stage x: 960 float4s, row j/15 -> padded slot
    const float4* s4 = (const float4*)(x + row0 * H);
    for (int jj = tid; jj < GR * 15; jj += NTHR)
      xs4[(jj / 15) * 16 + (jj % 15)] = s4[jj];
  }
  __syncthreads();

  const int hb = half * 7;  // half1 reads x float4s 7..14 (cols 28..59)

#define GX(s, a)                                                      \
  {                                                                   \
    const float4 xv = xs4[(p8 + (s)) * 16 + hb + kk];                 \
    a = fmaf(w.x, xv.x, a); a = fmaf(w.y, xv.y, a);                   \
    a = fmaf(w.z, xv.z, a); a = fmaf(w.w, xv.w, a);                   \
  }
#pragma unroll
  for (int p = 0; p < 8; ++p) {
    const int p8 = p * 8;
    float a0 = bi, a1 = bi, a2 = bi, a3 = bi;
    float a4 = bi, a5 = bi, a6 = bi, a7 = bi;
#pragma unroll
    for (int kk = 0; kk < 8; ++kk) {
      float4 w;
      switch (kk) {
        case 0: w = W0; break; case 1: w = W1; break;
        case 2: w = W2; break; case 3: w = W3; break;
        case 4: w = W4; break; case 5: w = W5; break;
        case 6: w = W6; break; default: w = W7; break;
      }
      GX(0, a0) GX(1, a1) GX(2, a2) GX(3, a3)
      GX(4, a4) GX(5, a5) GX(6, a6) GX(7, a7)
    }
    a0 += __shfl_xor(a0, 1); a1 += __shfl_xor(a1, 1);
    a2 += __shfl_xor(a2, 1); a3 += __shfl_xor(a3, 1);
    a4 += __shfl_xor(a4, 1); a5 += __shfl_xor(a5, 1);
    a6 += __shfl_xor(a6, 1); a7 += __shfl_xor(a7, 1);
    if (act && !half) {
      float* o = gi + (row0 + p8) * G + row;
      o[0 * G] = a0; o[1 * G] = a1; o[2 * G] = a2; o[3 * G] = a3;
      o[4 * G] = a4; o[5 * G] = a5; o[6 * G] = a6; o[7 * G] = a7;
    }
  }
#undef GX
}

// ---------------------------------------------------------------------------
// Recurrent GRU chunk, pair-split Whh dot. SCALAR_X: F=1 input term computed
// in-kernel; else `a` streams from precomputed gi (4-deep prefetch on even
// lanes). 2 barriers/step over 6 waves.
// ---------------------------------------------------------------------------
template <bool SCALAR_X, bool WRITE_YS, bool WRITE_PRED>
__global__ __launch_bounds__(NTHR, 1) void gru_rec_kernel(
    const float* __restrict__ gi,      // [nsteps][B][180] chunk-local (!SCALAR_X)
    const float* __restrict__ xsc,     // [B][T] (SCALAR_X)
    const float* __restrict__ Wih1,    // [180] (SCALAR_X)
    const float* __restrict__ bih1,    // [180] (SCALAR_X)
    const float* __restrict__ Whh, const float* __restrict__ bhh,
    const float* __restrict__ h_in, int h_in_stride,  // null => zeros
    float* __restrict__ ys_out,        // chunk base [nsteps][B][60]
    float* __restrict__ h_out,         // [B][60] carry
    float* __restrict__ enc_out,       // [b*180+j] or null
    float* __restrict__ pred_out,      // [B][T] (WRITE_PRED)
    const float* __restrict__ linW, const float* __restrict__ linb,
    int t0, int nsteps)
{
  const int tid = threadIdx.x;
  const int b = blockIdx.x;

  __shared__ __align__(16) float h_sh[64];
  __shared__ float Ar[60], Az[60], Nn[60], Hn[60];
  __shared__ float xs_seq[T];
  __shared__ float pv[64];

  const bool act = tid < 2 * G;
  const int row = (act ? tid : 0) >> 1;
  const int half = tid & 1;

  float4 W0, W1, W2, W3, W4, W5, W6, W7;
  LOADW8(&Whh[(size_t)row * H + half * 28]);
  const float bh = half ? 0.f : bhh[row];

  float wih0 = 0.f, bi0 = 0.f;
  if constexpr (SCALAR_X) {
    wih0 = half ? 0.f : Wih1[row];
    bi0 = half ? 0.f : bih1[row];
  }

  float linw = 0.f, lb = 0.f;
  if constexpr (WRITE_PRED) {
    linw = linW[tid < H ? tid : 0];
    lb = linb[0];
  }

  if (tid < 64) h_sh[tid] = (tid < H && h_in) ? h_in[(size_t)b * h_in_stride + tid] : 0.f;
  if constexpr (SCALAR_X) {
    for (int i = tid; i < nsteps; i += NTHR)
      xs_seq[i] = xsc[(size_t)b * T + t0 + i];
  }
  __syncthreads();

  const int g = row / H;
  const int j = row - g * H;
  const int hb = half * 7;
  const bool even = act && !half;

  float g0 = 0.f, g1 = 0.f, g2 = 0.f, g3 = 0.f;
  if constexpr (!SCALAR_X) {
    if (even) {
      g0 = gi[((size_t)0 * B + b) * G + row];
      g1 = gi[((size_t)1 * B + b) * G + row];
      g2 = gi[((size_t)2 * B + b) * G + row];
      g3 = gi[((size_t)3 * B + b) * G + row];
    }
  }

  for (int s = 0; s < nsteps; ++s) {
    float gn = 0.f;
    if constexpr (!SCALAR_X) {
      if (even && s + 4 < nsteps) gn = gi[((size_t)(s + 4) * B + b) * G + row];
    }

    if (act) {
      const float4* h4 = (const float4*)h_sh;
      float c0 = bh, c1 = 0.f;
#define HC(i, d) { const float4 hv = h4[hb + (i)];                    \
        d = fmaf(W##i.x, hv.x, d); d = fmaf(W##i.y, hv.y, d);         \
        d = fmaf(W##i.z, hv.z, d); d = fmaf(W##i.w, hv.w, d); }
      HC(0, c0) HC(1, c1) HC(2, c0) HC(3, c1)
      HC(4, c0) HC(5, c1) HC(6, c0) HC(7, c1)
#undef HC
      float c = c0 + c1;
      c += __shfl_xor(c, 1);
      if (!half) {
        float a;
        if constexpr (SCALAR_X) a = fmaf(wih0, xs_seq[s], bi0);
        else                    a = g0;
        if (g == 0)       Ar[j] = a + c;
        else if (g == 1)  Az[j] = a + c;
        else            { Nn[j] = a; Hn[j] = c; }
      }
    }
    if constexpr (!SCALAR_X) { g0 = g1; g1 = g2; g2 = g3; g3 = gn; }
    __syncthreads();

    if (tid < H) {
      const float rg = sigm(Ar[tid]);
      const float zg = sigm(Az[tid]);
      const float nv = tanh_fast(fmaf(rg, Hn[tid], Nn[tid]));
      const float hnew = fmaf(zg, h_sh[tid] - nv, nv);
      h_sh[tid] = hnew;
      if constexpr (WRITE_YS)
        ys_out[(size_t)s * B * H + (size_t)b * H + tid] = hnew;
      if constexpr (WRITE_PRED) pv[tid] = hnew * linw;
    }
    __syncthreads();

    if constexpr (WRITE_PRED) {
      if (tid < 64) {
        float v = (tid < H) ? pv[tid] : 0.f;
#pragma unroll
        for (int o = 32; o; o >>= 1) v += __shfl_xor(v, o);
        if (tid == 0) pred_out[(size_t)b * T + t0 + s] = v + lb;
      }
    }
  }

  if (tid < H) {
    h_out[(size_t)b * H + tid] = h_sh[tid];
    if (enc_out) enc_out[(size_t)b * G + tid] = h_sh[tid];
  }
}

// ---------------------------------------------------------------------------
// One layer = nch chunks of (optional gemm -> rec). The rec overwrites the ys
// chunk the gemm just consumed, so one ys buffer + one gi chunk buffer work.
// ---------------------------------------------------------------------------
template <bool SCALAR_X, bool WRITE_YS, bool WRITE_PRED>
void run_layer(const float* xsc,
               const float* Wih, const float* bih,
               const float* Whh, const float* bhh,
               const float* h_init_slot,            // stride 180, may be null
               float* enc_slot_out,                 // may be null
               float* ysA, float* gic, float* hio,
               float* pred, const float* linW, const float* linb,
               int nch, hipStream_t stream) {
  const int tn = T / nch;
  for (int c = 0; c < nch; ++c) {
    const int t0 = c * tn;
    if constexpr (!SCALAR_X) {
      gi_gemm_kernel<<<dim3((tn * B) / GR), dim3(NTHR), 0, stream>>>(
          ysA + (size_t)t0 * B * H, Wih, bih, gic);
    }
    gru_rec_kernel<SCALAR_X, WRITE_YS, WRITE_PRED>
        <<<dim3(B), dim3(NTHR), 0, stream>>>(
        gic, xsc, Wih, bih, Whh, bhh,
        c ? hio : h_init_slot, c ? H : G,
        ysA + (size_t)t0 * B * H, hio,
        (c == nch - 1) ? enc_slot_out : nullptr,
        pred, linW, linb, t0, tn);
  }
}

}  // namespace

extern "C" void kernel_launch(void* const* d_in, const int* in_sizes, int n_in,
                              void* d_out, int out_size, void* d_ws, size_t ws_size,
                              hipStream_t stream) {
  const float* inputs  = (const float*)d_in[0];
  const float* outputs = (const float*)d_in[1];
  const float* eW_ih0 = (const float*)d_in[2];  const float* eW_hh0 = (const float*)d_in[3];
  const float* eb_ih0 = (const float*)d_in[4];  const float* eb_hh0 = (const float*)d_in[5];
  const float* eW_ih1 = (const float*)d_in[6];  const float* eW_hh1 = (const float*)d_in[7];
  const float* eb_ih1 = (const float*)d_in[8];  const float* eb_hh1 = (const float*)d_in[9];
  const float* eW_ih2 = (const float*)d_in[10]; const float* eW_hh2 = (const float*)d_in[11];
  const float* eb_ih2 = (const float*)d_in[12]; const float* eb_hh2 = (const float*)d_in[13];
  const float* c1_Wih = (const float*)d_in[14]; const float* c1_Whh = (const float*)d_in[15];
  const float* c1_bih = (const float*)d_in[16]; const float* c1_bhh = (const float*)d_in[17];
  const float* c2_Wih = (const float*)d_in[18]; const float* c2_Whh = (const float*)d_in[19];
  const float* c2_bih = (const float*)d_in[20]; const float* c2_bhh = (const float*)d_in[21];
  const float* c3_Wih = (const float*)d_in[22]; const float* c3_Whh = (const float*)d_in[23];
  const float* c3_bih = (const float*)d_in[24]; const float* c3_bhh = (const float*)d_in[25];
  const float* lin_W  = (const float*)d_in[26]; const float* lin_b  = (const float*)d_in[27];

  float* pred = (float*)d_out;                 // [B][T]
  float* enc  = pred + (size_t)B * T;          // [B][3][60]

  const size_t seq = (size_t)T * B * H;        // ys elements

  int nch = 64;
  for (int c : {1, 2, 4, 8, 16, 32}) {
    const size_t need = seq * 4 + (size_t)(T / c) * B * G * 4 + (size_t)B * H * 4;
    if (ws_size >= need) { nch = c; break; }
  }

  float* ysA = (float*)d_ws;                        // [T][B][60] fp32
  float* gic = ysA + seq;                           // [(T/nch)][B][180] fp32
  float* hio = gic + (size_t)(T / nch) * B * G;     // [B][60] fp32

  // ---- encoder ----
  run_layer<true, true, false>(inputs, eW_ih0, eb_ih0, eW_hh0, eb_hh0,
                               nullptr, enc + 0,
                               ysA, gic, hio, pred, lin_W, lin_b, nch, stream);
  run_layer<false, true, false>(nullptr, eW_ih1, eb_ih1, eW_hh1, eb_hh1,
                                nullptr, enc + 60,
                                ysA, gic, hio, pred, lin_W, lin_b, nch, stream);
  run_layer<false, false, false>(nullptr, eW_ih2, eb_ih2, eW_hh2, eb_hh2,
                                 nullptr, enc + 120,
                                 ysA, gic, hio, pred, lin_W, lin_b, nch, stream);

  // ---- decoder: h1<-enc[2], h2<-enc[1], h3<-enc[0] ----
  run_layer<true, true, false>(outputs, c1_Wih, c1_bih, c1_Whh, c1_bhh,
                               enc + 120, nullptr,
                               ysA, gic, hio, pred, lin_W, lin_b, nch, stream);
  run_layer<false, true, false>(nullptr, c2_Wih, c2_bih, c2_Whh, c2_bhh,
                                enc + 60, nullptr,
                                ysA, gic, hio, pred, lin_W, lin_b, nch, stream);
  run_layer<false, false, true>(nullptr, c3_Wih, c3_bih, c3_Whh, c3_bhh,
                                enc + 0, nullptr,
                                ysA, gic, hio, pred, lin_W, lin_b, nch, stream);
}